// Round 4
// baseline (1155.476 us; speedup 1.0000x reference)
//
#include <hip/hip_runtime.h>

typedef unsigned short u16;
typedef unsigned int u32;

#define NN 50000
#define EE 250000
#define GG 512

typedef __bf16 bf16x8 __attribute__((ext_vector_type(8)));
typedef float  f32x4  __attribute__((ext_vector_type(4)));

__device__ __forceinline__ u16 f2bfu(float f) {
    __bf16 b = (__bf16)f; u16 u; __builtin_memcpy(&u, &b, 2); return u;
}

// ---------------------------------------------------------------------------
// Build swizzled B (We2 viewed as 1024x32, plus be2 as a 33rd K-step) in
// MFMA fragment order: Bg[kk*1024 + ct*512 + l*8 + j] = W[32*kk+8*(l>>4)+j][(l&15)+16*ct]
// ---------------------------------------------------------------------------
__global__ void prep_B(const float* __restrict__ We2, const float* __restrict__ be2,
                       u16* __restrict__ Bg) {
    int idx = blockIdx.x * blockDim.x + threadIdx.x;
    if (idx >= 33 * 1024) return;
    int kk = idx >> 10, off = idx & 1023;
    int ct = off >> 9, l = (off >> 3) & 63, j = off & 7;
    int q = l >> 4, c = l & 15, o = c + 16 * ct;
    float v;
    if (kk < 32) v = We2[(32 * kk + 8 * q + j) * 32 + o];   // We2 flat: k*1024 + h*32 + o
    else         v = be2[(8 * q + j) * 32 + o];             // bias step (t == 1)
    Bg[idx] = f2bfu(v);
}

// ---------------------------------------------------------------------------
// t = relu(edge_attr @ We1 + be1), stored bf16 [E][32]
// ---------------------------------------------------------------------------
__global__ void prep_edges(const float* __restrict__ ea, const float* __restrict__ We1,
                           const float* __restrict__ be1, u16* __restrict__ tmat) {
    int e = blockIdx.x * blockDim.x + threadIdx.x;
    if (e >= EE) return;
    const float4* ep = (const float4*)(ea + (size_t)e * 16);
    float a[16];
#pragma unroll
    for (int i = 0; i < 4; i++) {
        float4 v = ep[i];
        a[4 * i] = v.x; a[4 * i + 1] = v.y; a[4 * i + 2] = v.z; a[4 * i + 3] = v.w;
    }
    u32 outw[16];
#pragma unroll
    for (int p = 0; p < 16; p++) {
        float acc0 = be1[2 * p], acc1 = be1[2 * p + 1];
#pragma unroll
        for (int k = 0; k < 16; k++) {
            acc0 += a[k] * We1[k * 32 + 2 * p];
            acc1 += a[k] * We1[k * 32 + 2 * p + 1];
        }
        acc0 = fmaxf(acc0, 0.f); acc1 = fmaxf(acc1, 0.f);
        outw[p] = (u32)f2bfu(acc0) | ((u32)f2bfu(acc1) << 16);
    }
    uint4* op = (uint4*)(tmat + (size_t)e * 32);
#pragma unroll
    for (int i = 0; i < 4; i++)
        op[i] = make_uint4(outw[4 * i], outw[4 * i + 1], outw[4 * i + 2], outw[4 * i + 3]);
}

// ---------------------------------------------------------------------------
// h = relu(x @ W0 + b0); write f32 state + bf16 mirror
// ---------------------------------------------------------------------------
__global__ void lin0_k(const float* __restrict__ x, const float* __restrict__ W0,
                       const float* __restrict__ b0, float* __restrict__ hf,
                       u16* __restrict__ cur) {
    int n = blockIdx.x * blockDim.x + threadIdx.x;
    if (n >= NN) return;
    const float4* xp = (const float4*)(x + (size_t)n * 32);
    float a[32];
#pragma unroll
    for (int i = 0; i < 8; i++) {
        float4 v = xp[i];
        a[4 * i] = v.x; a[4 * i + 1] = v.y; a[4 * i + 2] = v.z; a[4 * i + 3] = v.w;
    }
    float o[32];
#pragma unroll 4
    for (int c = 0; c < 32; c++) {
        float acc = b0[c];
#pragma unroll
        for (int k = 0; k < 32; k++) acc += a[k] * W0[k * 32 + c];
        o[c] = fmaxf(acc, 0.f);
    }
    float4* hp = (float4*)(hf + (size_t)n * 32);
#pragma unroll
    for (int i = 0; i < 8; i++) hp[i] = make_float4(o[4 * i], o[4 * i + 1], o[4 * i + 2], o[4 * i + 3]);
    uint4* cp = (uint4*)(cur + (size_t)n * 32);
#pragma unroll
    for (int i = 0; i < 4; i++) {
        u32 p0 = (u32)f2bfu(o[8 * i + 0]) | ((u32)f2bfu(o[8 * i + 1]) << 16);
        u32 p1 = (u32)f2bfu(o[8 * i + 2]) | ((u32)f2bfu(o[8 * i + 3]) << 16);
        u32 p2 = (u32)f2bfu(o[8 * i + 4]) | ((u32)f2bfu(o[8 * i + 5]) << 16);
        u32 p3 = (u32)f2bfu(o[8 * i + 6]) | ((u32)f2bfu(o[8 * i + 7]) << 16);
        cp[i] = make_uint4(p0, p1, p2, p3);
    }
}

// ---------------------------------------------------------------------------
// histograms: in-degree per node, node count per graph
// ---------------------------------------------------------------------------
__global__ void hist_k(const int* __restrict__ ei, const int* __restrict__ batch,
                       int* __restrict__ degc, int* __restrict__ gcnt) {
    int i = blockIdx.x * blockDim.x + threadIdx.x;
    if (i < EE) atomicAdd(degc + ei[EE + i], 1);
    if (i < NN) atomicAdd(gcnt + batch[i], 1);
}

__global__ void degfin_k(const int* __restrict__ degc, float* __restrict__ dinv) {
    int n = blockIdx.x * blockDim.x + threadIdx.x;
    if (n >= NN) return;
    int c = degc[n];
    dinv[n] = 1.f / (float)(c > 0 ? c : 1);
}

// ---------------------------------------------------------------------------
// Message kernel: per 16-edge tile, msg = (t ⊗ s) @ We2~ via 66 MFMAs,
// scatter f32 atomics into agg. B staged in LDS in fragment order.
// ---------------------------------------------------------------------------
__global__ __launch_bounds__(512) void msg_k(const u16* __restrict__ cur,
                                             const u16* __restrict__ tmat,
                                             const int* __restrict__ ei,
                                             const u16* __restrict__ Bg,
                                             float* __restrict__ agg) {
    __shared__ uint4 Bl[4096];   // 64 KB: kk 0..31, fragment order
    const uint4* Bgv = (const uint4*)Bg;
    for (int i = threadIdx.x; i < 4096; i += 512) Bl[i] = Bgv[i];
    __syncthreads();
    const u16* Bl16 = (const u16*)Bl;

    int l = threadIdx.x & 63;
    int q = l >> 4, r = l & 15;
    int wid = (blockIdx.x * blockDim.x + threadIdx.x) >> 6;
    int nw  = (gridDim.x * blockDim.x) >> 6;

    for (int tile = wid; tile < EE / 16; tile += nw) {
        int eb = tile * 16;
        int srow = ei[eb + r];                                   // src of this lane's edge
        bf16x8 sv = *reinterpret_cast<const bf16x8*>(cur + (size_t)srow * 32 + q * 8);
        float sf[8];
#pragma unroll
        for (int j = 0; j < 8; j++) sf[j] = (float)sv[j];
        const uint4* tp = reinterpret_cast<const uint4*>(tmat + (size_t)(eb + r) * 32);
        f32x4 acc0 = {0.f, 0.f, 0.f, 0.f}, acc1 = {0.f, 0.f, 0.f, 0.f};
#pragma unroll
        for (int kq = 0; kq < 4; kq++) {
            uint4 tw4 = tp[kq];
            u32 tws[4] = {tw4.x, tw4.y, tw4.z, tw4.w};
#pragma unroll
            for (int du = 0; du < 4; du++) {
                u32 w = tws[du];
#pragma unroll
                for (int hl = 0; hl < 2; hl++) {
                    int kk = kq * 8 + du * 2 + hl;
                    float tf = __uint_as_float(hl ? (w & 0xffff0000u) : (w << 16));
                    bf16x8 av;
#pragma unroll
                    for (int j = 0; j < 8; j++) av[j] = (__bf16)(tf * sf[j]);
                    bf16x8 b0 = *reinterpret_cast<const bf16x8*>(Bl16 + kk * 1024 + l * 8);
                    bf16x8 b1 = *reinterpret_cast<const bf16x8*>(Bl16 + kk * 1024 + 512 + l * 8);
                    acc0 = __builtin_amdgcn_mfma_f32_16x16x32_bf16(av, b0, acc0, 0, 0, 0);
                    acc1 = __builtin_amdgcn_mfma_f32_16x16x32_bf16(av, b1, acc1, 0, 0, 0);
                }
            }
        }
        {   // bias step: u = s (t == 1); B rows = be2 reshaped (global, L1-resident)
            bf16x8 b0 = *reinterpret_cast<const bf16x8*>(Bg + 32 * 1024 + l * 8);
            bf16x8 b1 = *reinterpret_cast<const bf16x8*>(Bg + 32 * 1024 + 512 + l * 8);
            acc0 = __builtin_amdgcn_mfma_f32_16x16x32_bf16(sv, b0, acc0, 0, 0, 0);
            acc1 = __builtin_amdgcn_mfma_f32_16x16x32_bf16(sv, b1, acc1, 0, 0, 0);
        }
        // C/D: lane l reg j -> row 4q+j (edge), col l&15 (+16 for acc1)  [m89 layout]
#pragma unroll
        for (int j = 0; j < 4; j++) {
            int d = ei[EE + eb + 4 * q + j];
            atomicAdd(agg + (size_t)d * 32 + r,      acc0[j]);
            atomicAdd(agg + (size_t)d * 32 + 16 + r, acc1[j]);
        }
    }
}

// ---------------------------------------------------------------------------
// Node update: m = relu(agg/deg + h@Wroot + bconv); GRU (torch gate order r,z,n)
// all f32; 1 thread per node.
// ---------------------------------------------------------------------------
__global__ void node_update(float* __restrict__ hf, u16* __restrict__ cur,
                            const float* __restrict__ agg, const float* __restrict__ dinv,
                            const float* __restrict__ Wroot, const float* __restrict__ bconv,
                            const float* __restrict__ Wih, const float* __restrict__ bih,
                            const float* __restrict__ Whh, const float* __restrict__ bhh) {
    int n = blockIdx.x * blockDim.x + threadIdx.x;
    if (n >= NN) return;
    float hv[32], mv[32];
    const float4* hp = (const float4*)(hf + (size_t)n * 32);
#pragma unroll
    for (int i = 0; i < 8; i++) {
        float4 v = hp[i];
        hv[4 * i] = v.x; hv[4 * i + 1] = v.y; hv[4 * i + 2] = v.z; hv[4 * i + 3] = v.w;
    }
    float di = dinv[n];
#pragma unroll 4
    for (int c = 0; c < 32; c++) {
        float acc = bconv[c] + agg[(size_t)n * 32 + c] * di;
#pragma unroll
        for (int k = 0; k < 32; k++) acc += hv[k] * Wroot[k * 32 + c];
        mv[c] = fmaxf(acc, 0.f);
    }
    float rr[32], zz[32];
#pragma unroll 2
    for (int g = 0; g < 32; g++) {
        float s = bih[g] + bhh[g];
#pragma unroll
        for (int k = 0; k < 32; k++)
            s += mv[k] * Wih[g * 32 + k] + hv[k] * Whh[g * 32 + k];
        rr[g] = 1.f / (1.f + expf(-s));
    }
#pragma unroll 2
    for (int g = 0; g < 32; g++) {
        float s = bih[32 + g] + bhh[32 + g];
#pragma unroll
        for (int k = 0; k < 32; k++)
            s += mv[k] * Wih[(32 + g) * 32 + k] + hv[k] * Whh[(32 + g) * 32 + k];
        zz[g] = 1.f / (1.f + expf(-s));
    }
    float out[32];
#pragma unroll 2
    for (int g = 0; g < 32; g++) {
        float gi = bih[64 + g];
        float gh = bhh[64 + g];
#pragma unroll
        for (int k = 0; k < 32; k++) {
            gi += mv[k] * Wih[(64 + g) * 32 + k];
            gh += hv[k] * Whh[(64 + g) * 32 + k];
        }
        float nn = tanhf(gi + rr[g] * gh);
        out[g] = (1.f - zz[g]) * nn + zz[g] * hv[g];
    }
    float4* hw = (float4*)(hf + (size_t)n * 32);
#pragma unroll
    for (int i = 0; i < 8; i++)
        hw[i] = make_float4(out[4 * i], out[4 * i + 1], out[4 * i + 2], out[4 * i + 3]);
    uint4* cp = (uint4*)(cur + (size_t)n * 32);
#pragma unroll
    for (int i = 0; i < 4; i++) {
        u32 p0 = (u32)f2bfu(out[8 * i + 0]) | ((u32)f2bfu(out[8 * i + 1]) << 16);
        u32 p1 = (u32)f2bfu(out[8 * i + 2]) | ((u32)f2bfu(out[8 * i + 3]) << 16);
        u32 p2 = (u32)f2bfu(out[8 * i + 4]) | ((u32)f2bfu(out[8 * i + 5]) << 16);
        u32 p3 = (u32)f2bfu(out[8 * i + 6]) | ((u32)f2bfu(out[8 * i + 7]) << 16);
        cp[i] = make_uint4(p0, p1, p2, p3);
    }
}

__global__ void pool_k(const float* __restrict__ hf, const int* __restrict__ batch,
                       float* __restrict__ gsum) {
    int n = blockIdx.x * blockDim.x + threadIdx.x;
    if (n >= NN) return;
    int g = batch[n];
#pragma unroll 8
    for (int o = 0; o < 32; o++) atomicAdd(gsum + g * 32 + o, hf[(size_t)n * 32 + o]);
}

// ---------------------------------------------------------------------------
// Heads: OUTPUT IS FLOAT32 (reference returns f32; harness contract "else float*")
// ---------------------------------------------------------------------------
__global__ void head_k(const float* __restrict__ gsum, const int* __restrict__ gcnt,
                       const float* __restrict__ W1a, const float* __restrict__ b1a,
                       const float* __restrict__ W1b, const float* __restrict__ b1b,
                       const float* __restrict__ W2a, const float* __restrict__ b2a,
                       const float* __restrict__ W2b, const float* __restrict__ b2b,
                       float* __restrict__ dout) {
    int g = blockIdx.x * blockDim.x + threadIdx.x;
    if (g >= GG) return;
    int c0 = gcnt[g];
    float rc = 1.f / (float)(c0 > 0 ? c0 : 1);
    float p[32];
#pragma unroll
    for (int i = 0; i < 32; i++) p[i] = gsum[g * 32 + i] * rc;
    float lab = b1b[0];
#pragma unroll 4
    for (int c = 0; c < 32; c++) {
        float acc = b1a[c];
#pragma unroll
        for (int k = 0; k < 32; k++) acc += p[k] * W1a[k * 32 + c];
        lab += fmaxf(acc, 0.f) * W1b[c];
    }
    float d0 = b2b[0], d1 = b2b[1];
#pragma unroll 4
    for (int c = 0; c < 32; c++) {
        float acc = b2a[c];
#pragma unroll
        for (int k = 0; k < 32; k++) acc += p[k] * W2a[k * 32 + c];
        float t = fmaxf(acc, 0.f);
        d0 += t * W2b[c * 2];
        d1 += t * W2b[c * 2 + 1];
    }
    float mx = fmaxf(d0, d1);
    float ls = mx + logf(expf(d0 - mx) + expf(d1 - mx));
    dout[g] = lab;
    dout[GG + g * 2]     = d0 - ls;
    dout[GG + g * 2 + 1] = d1 - ls;
}

// ---------------------------------------------------------------------------
extern "C" void kernel_launch(void* const* d_in, const int* in_sizes, int n_in,
                              void* d_out, int out_size, void* d_ws, size_t ws_size,
                              hipStream_t stream) {
    const float* x   = (const float*)d_in[0];
    const float* ea  = (const float*)d_in[1];
    const int* ei    = (const int*)d_in[2];
    const int* batch = (const int*)d_in[3];
    // d_in[4] alpha: unused in forward (gradient reversal is identity)
    const float* W0 = (const float*)d_in[5],  *b0 = (const float*)d_in[6];
    const float* We1 = (const float*)d_in[7], *be1 = (const float*)d_in[8];
    const float* We2 = (const float*)d_in[9], *be2 = (const float*)d_in[10];
    const float* Wroot = (const float*)d_in[11], *bconv = (const float*)d_in[12];
    const float* Wih = (const float*)d_in[13], *bih = (const float*)d_in[14];
    const float* Whh = (const float*)d_in[15], *bhh = (const float*)d_in[16];
    const float* W1a = (const float*)d_in[17], *b1a = (const float*)d_in[18];
    const float* W1b = (const float*)d_in[19], *b1b = (const float*)d_in[20];
    const float* W2a = (const float*)d_in[21], *b2a = (const float*)d_in[22];
    const float* W2b = (const float*)d_in[23], *b2b = (const float*)d_in[24];
    float* dout = (float*)d_out;

    char* w = (char*)d_ws;
    u16*   tmat = (u16*)w;    w += (size_t)EE * 32 * 2;   // 16,000,000
    u16*   Bg   = (u16*)w;    w += 33 * 1024 * 2;         // 67,584
    float* hf   = (float*)w;  w += (size_t)NN * 32 * 4;   // 6,400,000
    u16*   cur  = (u16*)w;    w += (size_t)NN * 32 * 2;   // 3,200,000
    float* agg  = (float*)w;  w += (size_t)NN * 32 * 4;   // 6,400,000
    float* dinv = (float*)w;  w += 200192;
    int*   degc = (int*)w;    w += 200192;
    float* gsum = (float*)w;  w += (size_t)GG * 32 * 4;   // 65,536
    int*   gcnt = (int*)w;    w += 2048;

    hipMemsetAsync(degc, 0, NN * 4, stream);
    hipMemsetAsync(gcnt, 0, GG * 4, stream);
    hipMemsetAsync(gsum, 0, GG * 32 * 4, stream);

    prep_B<<<132, 256, 0, stream>>>(We2, be2, Bg);
    prep_edges<<<(EE + 255) / 256, 256, 0, stream>>>(ea, We1, be1, tmat);
    lin0_k<<<(NN + 255) / 256, 256, 0, stream>>>(x, W0, b0, hf, cur);
    hist_k<<<(EE + 255) / 256, 256, 0, stream>>>(ei, batch, degc, gcnt);
    degfin_k<<<(NN + 255) / 256, 256, 0, stream>>>(degc, dinv);

    for (int it = 0; it < 3; it++) {
        hipMemsetAsync(agg, 0, (size_t)NN * 32 * 4, stream);
        msg_k<<<512, 512, 0, stream>>>(cur, tmat, ei, Bg, agg);
        node_update<<<(NN + 127) / 128, 128, 0, stream>>>(hf, cur, agg, dinv,
                                                          Wroot, bconv, Wih, bih, Whh, bhh);
    }

    pool_k<<<(NN + 255) / 256, 256, 0, stream>>>(hf, batch, gsum);
    head_k<<<2, 256, 0, stream>>>(gsum, gcnt, W1a, b1a, W1b, b1b, W2a, b2a, W2b, b2b, dout);
}